// Round 4
// baseline (2563.970 us; speedup 1.0000x reference)
//
#include <hip/hip_runtime.h>

// ============================================================================
// TemporalPointNet (PointNet++ style) forward on MI355X.
// B=2, T=4 -> BT=8 "batches", N=4096 points, 4 coords (xyz + t).
// SA1: npoint=512, r=0.2, K=32, C_in=4,  MLP 64,64,128
// SA2: npoint=128, r=0.4, K=64, C_in=131, MLP 128,128,256
// SA3: group_all,          K=128, C_in=259, MLP 256,512,1024
// Output: (2,4,1024) f32 = 8192 floats.
//
// R4: FPS latency attack — 64-bit (dist,~idx) keys, radix-8 wave argmax
// (2 rounds x 7 independent shuffles instead of 6 dependent steps), winner
// coords via one broadcast ds_read_b128 from a float4 LDS table, one
// barrier/iter (parity dbuf). GEMM: 128x64 / 128x128 tiles with 8x4 / 8x8
// per-thread accumulators (VALU-limited instead of LDS-limited); K-order
// unchanged -> bit-identical outputs.
// ============================================================================

// ---------------- FPS: one block (NT threads) per batch ----------------
// Point n owned by thread (n % NT), item (n / NT). Matches jnp semantics:
// dist init 1e10, d = ((dx^2+dy^2)+dz^2) with rn ops (no fma contraction),
// argmax picks FIRST occurrence of max (lowest index on ties).
template<int NT, int ITEMS, int STRIDE>
__global__ __launch_bounds__(NT) void fps_fast(
    const float* __restrict__ pts, int npoint,
    int* __restrict__ outIdx, float* __restrict__ outXyz)
{
    constexpr int N = NT * ITEMS;
    constexpr int NW = NT / 64;
    __shared__ float4 scoord[N];                 // winner-coord lookup table
    __shared__ unsigned long long wkey[2][NW];   // per-wave winner keys (parity dbuf)

    const int b = blockIdx.x;
    const int tid = threadIdx.x;
    const int wid = tid >> 6;
    const int lane = tid & 63;
    const float* P = pts + (size_t)b * N * STRIDE;

    float px[ITEMS], py[ITEMS], pz[ITEMS], dloc[ITEMS];
#pragma unroll
    for (int w = 0; w < ITEMS; ++w) {
        int n = tid + w * NT;
        float x, y, z;
        if (STRIDE == 4) {
            float4 v = *(const float4*)(P + (size_t)n * 4);
            x = v.x; y = v.y; z = v.z;
        } else {
            x = P[(size_t)n * STRIDE + 0];
            y = P[(size_t)n * STRIDE + 1];
            z = P[(size_t)n * STRIDE + 2];
        }
        px[w] = x; py[w] = y; pz[w] = z;
        scoord[n] = make_float4(x, y, z, 0.f);
        dloc[w] = 1e10f;
    }
    __syncthreads();
    float4 c0 = scoord[0];
    float cx = c0.x, cy = c0.y, cz = c0.z;
    int far = 0;

    auto umax = [](unsigned long long a, unsigned long long b) {
        return a > b ? a : b;
    };

    for (int i = 0; i < npoint; ++i) {
        if (tid == 0) {
            outIdx[(size_t)b * npoint + i] = far;
            outXyz[((size_t)b * npoint + i) * 3 + 0] = cx;
            outXyz[((size_t)b * npoint + i) * 3 + 1] = cy;
            outXyz[((size_t)b * npoint + i) * 3 + 2] = cz;
        }
        // dist update + thread-local argmax (strict > keeps lowest item idx)
        float bestV = -1.0f;
        int bestW = 0;
#pragma unroll
        for (int w = 0; w < ITEMS; ++w) {
            float dx = __fsub_rn(px[w], cx);
            float dy = __fsub_rn(py[w], cy);
            float dz = __fsub_rn(pz[w], cz);
            float d = __fadd_rn(__fadd_rn(__fmul_rn(dx, dx), __fmul_rn(dy, dy)),
                                __fmul_rn(dz, dz));
            float dd = fminf(dloc[w], d);
            dloc[w] = dd;
            if (dd > bestV) { bestV = dd; bestW = w; }
        }
        int bestN = tid + bestW * NT;   // n grows with w -> lowest n on tie
        // key: dist (nonneg float, bit order == value order) then min-index
        unsigned long long key =
            ((unsigned long long)__float_as_uint(bestV) << 32) |
            (unsigned long long)(0xFFFFFFFFu ^ (unsigned)bestN);

        // wave argmax: radix-8 — round 1: masks 1..7 (independent shuffles)
        {
            unsigned long long t0 = __shfl_xor(key, 1);
            unsigned long long t1 = __shfl_xor(key, 2);
            unsigned long long t2 = __shfl_xor(key, 3);
            unsigned long long t3 = __shfl_xor(key, 4);
            unsigned long long t4 = __shfl_xor(key, 5);
            unsigned long long t5 = __shfl_xor(key, 6);
            unsigned long long t6 = __shfl_xor(key, 7);
            key = umax(umax(umax(key, t0), umax(t1, t2)),
                       umax(umax(t3, t4), umax(t5, t6)));
        }
        // round 2: masks 8,16,...,56 (independent shuffles of group max)
        {
            unsigned long long t0 = __shfl_xor(key, 8);
            unsigned long long t1 = __shfl_xor(key, 16);
            unsigned long long t2 = __shfl_xor(key, 24);
            unsigned long long t3 = __shfl_xor(key, 32);
            unsigned long long t4 = __shfl_xor(key, 40);
            unsigned long long t5 = __shfl_xor(key, 48);
            unsigned long long t6 = __shfl_xor(key, 56);
            key = umax(umax(umax(key, t0), umax(t1, t2)),
                       umax(umax(t3, t4), umax(t5, t6)));
        }
        const int par = i & 1;
        if (lane == 0) wkey[par][wid] = key;
        __syncthreads();   // single barrier per iteration
        unsigned long long kb = wkey[par][0];
#pragma unroll
        for (int w2 = 1; w2 < NW; ++w2) kb = umax(kb, wkey[par][w2]);
        far = (int)(0xFFFFFFFFu ^ (unsigned)kb);
        float4 cc = scoord[far];   // broadcast read, conflict-free
        cx = cc.x; cy = cc.y; cz = cc.z;
    }
}

// ---------------- query_ball: one wave per center ----------------
// First nsample indices (ascending) with d2 <= r2; pad with first hit.
__global__ __launch_bounds__(256) void query_ball_kernel(
    const float* __restrict__ xyz, int stride, int N,
    const float* __restrict__ centers, int nCenters, int S,
    float r2, int nsample, int* __restrict__ outIdx)
{
    int gw = (blockIdx.x * 256 + threadIdx.x) >> 6;
    int lane = threadIdx.x & 63;
    if (gw >= nCenters) return;
    int b = gw / S;
    const float* P = xyz + (size_t)b * N * stride;
    float cx = centers[(size_t)gw * 3 + 0];
    float cy = centers[(size_t)gw * 3 + 1];
    float cz = centers[(size_t)gw * 3 + 2];
    int* out = outIdx + (size_t)gw * nsample;
    int cnt = 0;
    int firstIdx = 0;
    bool haveFirst = false;
    for (int base = 0; base < N && cnt < nsample; base += 64) {
        int n = base + lane;
        bool inb = false;
        if (n < N) {
            float dx = __fsub_rn(cx, P[(size_t)n * stride + 0]);
            float dy = __fsub_rn(cy, P[(size_t)n * stride + 1]);
            float dz = __fsub_rn(cz, P[(size_t)n * stride + 2]);
            float d = __fadd_rn(__fadd_rn(__fmul_rn(dx, dx), __fmul_rn(dy, dy)),
                                __fmul_rn(dz, dz));
            inb = !(d > r2);
        }
        unsigned long long mask = __ballot(inb);
        if (mask) {
            if (!haveFirst) { firstIdx = base + __builtin_ctzll(mask); haveFirst = true; }
            if (inb) {
                int pos = cnt + __builtin_popcountll(mask & ((1ull << lane) - 1ull));
                if (pos < nsample) out[pos] = n;
            }
            cnt += (int)__builtin_popcountll(mask);
        }
    }
    if (cnt > nsample) cnt = nsample;
    for (int p = cnt + lane; p < nsample; p += 64) out[p] = firstIdx;
}

// ---------------- grouping kernels ----------------
__global__ __launch_bounds__(256) void group1_kernel(
    const float* __restrict__ in, const int* __restrict__ qb,
    const float* __restrict__ ctr, float* __restrict__ out)
{
    int i = blockIdx.x * 256 + threadIdx.x;
    if (i >= 8 * 512 * 32) return;
    int bs = i / 32;
    int b = i / (512 * 32);
    int idx = qb[i];
    idx = (idx < 0) ? 0 : (idx > 4095 ? 4095 : idx);
    const float* p = in + ((size_t)b * 4096 + idx) * 4;
    const float* c = ctr + (size_t)bs * 3;
    float* o = out + (size_t)i * 4;
    o[0] = __fsub_rn(p[0], c[0]);
    o[1] = __fsub_rn(p[1], c[1]);
    o[2] = __fsub_rn(p[2], c[2]);
    o[3] = p[3];
}

__global__ __launch_bounds__(256) void group2_kernel(
    const float* __restrict__ xyz, const float* __restrict__ feat,
    const int* __restrict__ qb, const float* __restrict__ ctr,
    float* __restrict__ out)
{
    int i = blockIdx.x * 256 + threadIdx.x;
    if (i >= 65536 * 131) return;
    int sk = i / 131;
    int c = i - sk * 131;
    int b = sk / (128 * 64);
    int bs = sk / 64;
    int idx = qb[sk];
    idx = (idx < 0) ? 0 : (idx > 511 ? 511 : idx);
    float v;
    if (c < 3) v = __fsub_rn(xyz[((size_t)b * 512 + idx) * 3 + c], ctr[(size_t)bs * 3 + c]);
    else       v = feat[((size_t)b * 512 + idx) * 128 + (c - 3)];
    out[i] = v;
}

__global__ __launch_bounds__(256) void group3_kernel(
    const float* __restrict__ ctr2, const float* __restrict__ feat2,
    float* __restrict__ out)
{
    int i = blockIdx.x * 256 + threadIdx.x;
    if (i >= 1024 * 259) return;
    int sk = i / 259;
    int c = i - sk * 259;
    out[i] = (c < 3) ? ctr2[(size_t)sk * 3 + c] : feat2[(size_t)sk * 256 + (c - 3)];
}

// ---------------- GEMM: Y[M,O] = act(X[M,C]) * W[O,C]^T ----------------
// act(x) = applyAct ? relu(x*scale[c]+shift[c]) : x   (BN of PREVIOUS layer)
// BM x BN tile, 256 threads, TM x TN per thread, BK=32. Per-element K-order
// is ascending kk across all k0 -> bit-identical to previous rounds.
template<int BM, int BN, int TM, int TN>
__global__ __launch_bounds__(256) void gemm_bn(
    const float* __restrict__ X, const float* __restrict__ W,
    float* __restrict__ Y,
    const float* __restrict__ scale, const float* __restrict__ shift,
    int applyAct, int M, int C, int O)
{
    constexpr int BK = 32;
    constexpr int PAD = 4;   // keeps rows 16B-aligned for b128 fragment reads
    __shared__ float Xs[BK][BM + PAD];
    __shared__ float Ws[BK][BN + PAD];
    const int m0 = blockIdx.x * BM;
    const int o0 = blockIdx.y * BN;
    const int tid = threadIdx.x;
    const int tx = tid % (BN / TN);
    const int ty = tid / (BN / TN);
    float acc[TM][TN] = {};
    for (int k0 = 0; k0 < C; k0 += BK) {
#pragma unroll
        for (int i = 0; i < (BM * BK) / 256; ++i) {
            int l = tid + i * 256;
            int r = l >> 5, kk = l & 31;
            int c = k0 + kk;
            float xv = 0.f;
            if (c < C) {
                xv = X[(size_t)(m0 + r) * C + c];
                if (applyAct) xv = fmaxf(xv * scale[c] + shift[c], 0.f);
            }
            Xs[kk][r] = xv;
        }
#pragma unroll
        for (int i = 0; i < (BN * BK) / 256; ++i) {
            int l = tid + i * 256;
            int r = l >> 5, kk = l & 31;
            int c = k0 + kk;
            Ws[kk][r] = (c < C) ? W[(size_t)(o0 + r) * C + c] : 0.f;
        }
        __syncthreads();
#pragma unroll
        for (int kk = 0; kk < BK; ++kk) {
            float a[TM], bv[TN];
#pragma unroll
            for (int i = 0; i < TM; ++i) a[i] = Xs[kk][ty * TM + i];
#pragma unroll
            for (int j = 0; j < TN; ++j) bv[j] = Ws[kk][tx * TN + j];
#pragma unroll
            for (int i = 0; i < TM; ++i)
#pragma unroll
                for (int j = 0; j < TN; ++j)
                    acc[i][j] += a[i] * bv[j];
        }
        __syncthreads();
    }
#pragma unroll
    for (int i = 0; i < TM; ++i) {
        int m = m0 + ty * TM + i;
#pragma unroll
        for (int j = 0; j < TN; ++j) {
            int o = o0 + tx * TN + j;
            Y[(size_t)m * O + o] = acc[i][j];
        }
    }
}

// ---------------- per-channel partial sum / sumsq (deterministic) ----------
__global__ __launch_bounds__(256) void stats_partial(
    const float* __restrict__ Y, double* __restrict__ part, int M, int O, int YB)
{
    int olane = threadIdx.x & 63;
    int mlane = threadIdx.x >> 6;
    int o = blockIdx.x * 64 + olane;
    int yb = blockIdx.y;
    int mbase = yb * 1024;
    int mend = min(M, mbase + 1024);
    double s = 0.0, s2 = 0.0;
    for (int m = mbase + mlane; m < mend; m += 4) {
        float v = Y[(size_t)m * O + o];
        s += (double)v;
        s2 += (double)v * (double)v;
    }
    __shared__ double sd[512];
    sd[threadIdx.x] = s;
    sd[256 + threadIdx.x] = s2;
    __syncthreads();
    if (mlane == 0) {
        double t  = sd[olane] + sd[64 + olane] + sd[128 + olane] + sd[192 + olane];
        double t2 = sd[256 + olane] + sd[320 + olane] + sd[384 + olane] + sd[448 + olane];
        part[(size_t)o * YB + yb] = t;
        part[(size_t)O * YB + (size_t)o * YB + yb] = t2;
    }
}

__global__ __launch_bounds__(256) void finalize_bn(
    const double* __restrict__ part, const float* __restrict__ g,
    const float* __restrict__ bb, float* __restrict__ scale,
    float* __restrict__ shift, int O, int YB, double invM)
{
    int o = blockIdx.x * 256 + threadIdx.x;
    if (o >= O) return;
    double s = 0.0, s2 = 0.0;
    for (int yb = 0; yb < YB; ++yb) {
        s  += part[(size_t)o * YB + yb];
        s2 += part[(size_t)O * YB + (size_t)o * YB + yb];
    }
    double mean = s * invM;
    double var = s2 * invM - mean * mean;
    float varf = (float)var;
    if (varf < 0.f) varf = 0.f;
    float sc = g[o] * rsqrtf(varf + 1e-5f);
    float sh = bb[o] - (float)mean * sc;
    scale[o] = sc;
    shift[o] = sh;
}

__global__ __launch_bounds__(256) void bn_relu_max(
    const float* __restrict__ Y, const float* __restrict__ scale,
    const float* __restrict__ shift, float* __restrict__ out,
    int Stot, int K, int O)
{
    int idx = blockIdx.x * 256 + threadIdx.x;
    if (idx >= Stot * O) return;
    int s = idx / O;
    int o = idx - s * O;
    const float* base = Y + (size_t)s * K * O + o;
    float sc = scale[o], sh = shift[o];
    float mx = 0.f;
    for (int k = 0; k < K; ++k) {
        float v = base[(size_t)k * O] * sc + sh;
        v = fmaxf(v, 0.f);
        mx = fmaxf(mx, v);
    }
    out[idx] = mx;
}

// ============================================================================
extern "C" void kernel_launch(void* const* d_in, const int* in_sizes, int n_in,
                              void* d_out, int out_size, void* d_ws, size_t ws_size,
                              hipStream_t stream)
{
    const float* xin = (const float*)d_in[0];
    const float* w[9]; const float* g[9]; const float* bb[9];
    for (int i = 0; i < 9; ++i) {
        w[i]  = (const float*)d_in[1 + 3 * i];
        g[i]  = (const float*)d_in[2 + 3 * i];
        bb[i] = (const float*)d_in[3 + 3 * i];
    }

    char* base = (char*)d_ws;
    size_t off = 0;
    auto alloc = [&](size_t bytes) -> void* {
        void* p = base + off;
        off = (off + bytes + 255) & ~(size_t)255;
        return p;
    };
    int*    fps1   = (int*)alloc((size_t)4096 * 4);
    int*    qb1    = (int*)alloc((size_t)131072 * 4);
    int*    fps2   = (int*)alloc((size_t)1024 * 4);
    int*    qb2    = (int*)alloc((size_t)65536 * 4);
    float*  nx1    = (float*)alloc((size_t)12288 * 4);
    float*  nx2    = (float*)alloc((size_t)3072 * 4);
    float*  feat1  = (float*)alloc((size_t)524288 * 4);
    float*  feat2  = (float*)alloc((size_t)262144 * 4);
    double* part   = (double*)alloc((size_t)65536 * 8);
    float*  scales = (float*)alloc((size_t)9 * 1024 * 4);
    float*  shifts = (float*)alloc((size_t)9 * 1024 * 4);
    float*  A      = (float*)alloc((size_t)16777216 * 4);
    float*  BG     = (float*)alloc((size_t)8585216 * 4);
    if (off > ws_size) return;

    // Every call must be bit-identical regardless of harness ws poison.
    hipMemsetAsync(d_ws, 0, off, stream);

    // ---------------- SA1 ----------------
    fps_fast<512, 8, 4><<<8, 512, 0, stream>>>(xin, 512, fps1, nx1);
    query_ball_kernel<<<(8 * 512 * 64) / 256, 256, 0, stream>>>(
        xin, 4, 4096, nx1, 8 * 512, 512, 0.04f, 32, qb1);
    group1_kernel<<<131072 / 256, 256, 0, stream>>>(xin, qb1, nx1, BG);

    gemm_bn<128, 64, 8, 4><<<dim3(1024, 1), 256, 0, stream>>>(BG, w[0], A, nullptr, nullptr, 0, 131072, 4, 64);
    stats_partial<<<dim3(1, 128), 256, 0, stream>>>(A, part, 131072, 64, 128);
    finalize_bn<<<1, 256, 0, stream>>>(part, g[0], bb[0], scales + 0 * 1024, shifts + 0 * 1024, 64, 128, 1.0 / 131072.0);
    gemm_bn<128, 64, 8, 4><<<dim3(1024, 1), 256, 0, stream>>>(A, w[1], BG, scales + 0 * 1024, shifts + 0 * 1024, 1, 131072, 64, 64);
    stats_partial<<<dim3(1, 128), 256, 0, stream>>>(BG, part, 131072, 64, 128);
    finalize_bn<<<1, 256, 0, stream>>>(part, g[1], bb[1], scales + 1 * 1024, shifts + 1 * 1024, 64, 128, 1.0 / 131072.0);
    gemm_bn<128, 128, 8, 8><<<dim3(1024, 1), 256, 0, stream>>>(BG, w[2], A, scales + 1 * 1024, shifts + 1 * 1024, 1, 131072, 64, 128);
    stats_partial<<<dim3(2, 128), 256, 0, stream>>>(A, part, 131072, 128, 128);
    finalize_bn<<<1, 256, 0, stream>>>(part, g[2], bb[2], scales + 2 * 1024, shifts + 2 * 1024, 128, 128, 1.0 / 131072.0);
    bn_relu_max<<<(4096 * 128) / 256, 256, 0, stream>>>(A, scales + 2 * 1024, shifts + 2 * 1024, feat1, 4096, 32, 128);

    // ---------------- SA2 ----------------
    fps_fast<512, 1, 3><<<8, 512, 0, stream>>>(nx1, 128, fps2, nx2);
    query_ball_kernel<<<(8 * 128 * 64) / 256, 256, 0, stream>>>(
        nx1, 3, 512, nx2, 8 * 128, 128, 0.16f, 64, qb2);
    group2_kernel<<<(65536 * 131) / 256, 256, 0, stream>>>(nx1, feat1, qb2, nx2, BG);

    gemm_bn<128, 128, 8, 8><<<dim3(512, 1), 256, 0, stream>>>(BG, w[3], A, nullptr, nullptr, 0, 65536, 131, 128);
    stats_partial<<<dim3(2, 64), 256, 0, stream>>>(A, part, 65536, 128, 64);
    finalize_bn<<<1, 256, 0, stream>>>(part, g[3], bb[3], scales + 3 * 1024, shifts + 3 * 1024, 128, 64, 1.0 / 65536.0);
    gemm_bn<128, 128, 8, 8><<<dim3(512, 1), 256, 0, stream>>>(A, w[4], BG, scales + 3 * 1024, shifts + 3 * 1024, 1, 65536, 128, 128);
    stats_partial<<<dim3(2, 64), 256, 0, stream>>>(BG, part, 65536, 128, 64);
    finalize_bn<<<1, 256, 0, stream>>>(part, g[4], bb[4], scales + 4 * 1024, shifts + 4 * 1024, 128, 64, 1.0 / 65536.0);
    gemm_bn<128, 128, 8, 8><<<dim3(512, 2), 256, 0, stream>>>(BG, w[5], A, scales + 4 * 1024, shifts + 4 * 1024, 1, 65536, 128, 256);
    stats_partial<<<dim3(4, 64), 256, 0, stream>>>(A, part, 65536, 256, 64);
    finalize_bn<<<1, 256, 0, stream>>>(part, g[5], bb[5], scales + 5 * 1024, shifts + 5 * 1024, 256, 64, 1.0 / 65536.0);
    bn_relu_max<<<(1024 * 256) / 256, 256, 0, stream>>>(A, scales + 5 * 1024, shifts + 5 * 1024, feat2, 1024, 64, 256);

    // ---------------- SA3 (group_all) ----------------
    group3_kernel<<<(1024 * 259 + 255) / 256, 256, 0, stream>>>(nx2, feat2, BG);

    gemm_bn<128, 128, 8, 8><<<dim3(8, 2), 256, 0, stream>>>(BG, w[6], A, nullptr, nullptr, 0, 1024, 259, 256);
    stats_partial<<<dim3(4, 1), 256, 0, stream>>>(A, part, 1024, 256, 1);
    finalize_bn<<<1, 256, 0, stream>>>(part, g[6], bb[6], scales + 6 * 1024, shifts + 6 * 1024, 256, 1, 1.0 / 1024.0);
    gemm_bn<128, 128, 8, 8><<<dim3(8, 4), 256, 0, stream>>>(A, w[7], BG, scales + 6 * 1024, shifts + 6 * 1024, 1, 1024, 256, 512);
    stats_partial<<<dim3(8, 1), 256, 0, stream>>>(BG, part, 1024, 512, 1);
    finalize_bn<<<2, 256, 0, stream>>>(part, g[7], bb[7], scales + 7 * 1024, shifts + 7 * 1024, 512, 1, 1.0 / 1024.0);
    gemm_bn<128, 128, 8, 8><<<dim3(8, 8), 256, 0, stream>>>(BG, w[8], A, scales + 7 * 1024, shifts + 7 * 1024, 1, 1024, 512, 1024);
    stats_partial<<<dim3(16, 1), 256, 0, stream>>>(A, part, 1024, 1024, 1);
    finalize_bn<<<4, 256, 0, stream>>>(part, g[8], bb[8], scales + 8 * 1024, shifts + 8 * 1024, 1024, 1, 1.0 / 1024.0);
    bn_relu_max<<<(8 * 1024) / 256, 256, 0, stream>>>(A, scales + 8 * 1024, shifts + 8 * 1024, (float*)d_out, 8, 128, 1024);
}

// Round 6
// 1773.036 us; speedup vs baseline: 1.4461x; 1.4461x over previous
//
#include <hip/hip_runtime.h>

// ============================================================================
// TemporalPointNet (PointNet++ style) forward on MI355X.
// B=2, T=4 -> BT=8 "batches", N=4096 points, 4 coords (xyz + t).
// SA1: npoint=512, r=0.2, K=32, C_in=4,  MLP 64,64,128
// SA2: npoint=128, r=0.4, K=64, C_in=131, MLP 128,128,256
// SA3: group_all,          K=128, C_in=259, MLP 256,512,1024
// Output: (2,4,1024) f32 = 8192 floats.
//
// R6: R5's plain-bf16 MFMA failed absmax (0.28 > 0.123) — input quantization,
// not layout. Fix: split-precision bf16 (hi+lo), D = Ah*Bh + Ah*Bl + Al*Bh
// -> ~16-bit effective mantissa, error back to f32-GEMM levels, still MFMA
// rate (3 mfma / fragment pair). FPS stays R5 (binary-tree u64-key argmax,
// 12 DS-ops/wave/iter; R4's radix-8 was DS-throughput-bound).
// ============================================================================

typedef short s16x8 __attribute__((ext_vector_type(8)));
typedef float f32x4 __attribute__((ext_vector_type(4)));

__device__ __forceinline__ unsigned short f2bf_rne(float f) {
    unsigned u = __float_as_uint(f);
    u += 0x7FFFu + ((u >> 16) & 1u);
    return (unsigned short)(u >> 16);
}
// split f32 -> (hi, lo) bf16 pair: hi = rne(v), lo = rne(v - hi)
__device__ __forceinline__ void f2bf_split(float v, unsigned short& hi,
                                           unsigned short& lo) {
    unsigned u = __float_as_uint(v);
    unsigned r = u + 0x7FFFu + ((u >> 16) & 1u);
    hi = (unsigned short)(r >> 16);
    float vh = __uint_as_float(r & 0xFFFF0000u);
    lo = f2bf_rne(v - vh);
}

__device__ __forceinline__ unsigned long long umax64(unsigned long long a,
                                                     unsigned long long b) {
    return a > b ? a : b;
}

// ---------------- FPS (multi-wave): one block (NT thr) per batch ------------
// Point n owned by thread (n % NT), item (n / NT). Matches jnp semantics:
// dist init 1e10, d = ((dx^2+dy^2)+dz^2) with rn ops (no fma contraction),
// argmax picks FIRST occurrence of max (lowest index on ties) via u64 key
// (dist_bits<<32)|~n  ->  max key == max dist, then min index.
template<int NT, int ITEMS, int STRIDE>
__global__ __launch_bounds__(NT) void fps_block(
    const float* __restrict__ pts, int npoint,
    int* __restrict__ outIdx, float* __restrict__ outXyz)
{
    constexpr int N = NT * ITEMS;
    constexpr int NW = NT / 64;
    __shared__ float4 scoord[N];
    __shared__ unsigned long long wkey[2][NW];

    const int b = blockIdx.x;
    const int tid = threadIdx.x;
    const int wid = tid >> 6;
    const int lane = tid & 63;
    const float* P = pts + (size_t)b * N * STRIDE;

    float px[ITEMS], py[ITEMS], pz[ITEMS], dloc[ITEMS];
#pragma unroll
    for (int w = 0; w < ITEMS; ++w) {
        int n = tid + w * NT;
        float x, y, z;
        if (STRIDE == 4) {
            float4 v = *(const float4*)(P + (size_t)n * 4);
            x = v.x; y = v.y; z = v.z;
        } else {
            x = P[(size_t)n * STRIDE + 0];
            y = P[(size_t)n * STRIDE + 1];
            z = P[(size_t)n * STRIDE + 2];
        }
        px[w] = x; py[w] = y; pz[w] = z;
        scoord[n] = make_float4(x, y, z, 0.f);
        dloc[w] = 1e10f;
    }
    __syncthreads();
    float4 c0 = scoord[0];
    float cx = c0.x, cy = c0.y, cz = c0.z;
    int far = 0;

    for (int i = 0; i < npoint; ++i) {
        if (tid == 0) {
            outIdx[(size_t)b * npoint + i] = far;
            outXyz[((size_t)b * npoint + i) * 3 + 0] = cx;
            outXyz[((size_t)b * npoint + i) * 3 + 1] = cy;
            outXyz[((size_t)b * npoint + i) * 3 + 2] = cz;
        }
        float bestV = -1.0f;
        int bestW = 0;
#pragma unroll
        for (int w = 0; w < ITEMS; ++w) {
            float dx = __fsub_rn(px[w], cx);
            float dy = __fsub_rn(py[w], cy);
            float dz = __fsub_rn(pz[w], cz);
            float d = __fadd_rn(__fadd_rn(__fmul_rn(dx, dx), __fmul_rn(dy, dy)),
                                __fmul_rn(dz, dz));
            float dd = fminf(dloc[w], d);
            dloc[w] = dd;
            if (dd > bestV) { bestV = dd; bestW = w; }  // strict > : lowest w kept
        }
        int bestN = tid + bestW * NT;   // n grows with w -> min n on tie
        unsigned long long key =
            ((unsigned long long)__float_as_uint(bestV) << 32) |
            (unsigned long long)(0xFFFFFFFFu ^ (unsigned)bestN);
        // binary-tree wave argmax: 6 steps, 12 b32 DS ops total
#pragma unroll
        for (int off = 1; off < 64; off <<= 1) {
            unsigned long long ok = __shfl_xor(key, off);
            if (ok > key) key = ok;
        }
        const int par = i & 1;
        if (lane == 0) wkey[par][wid] = key;
        __syncthreads();   // single barrier per iteration (parity dbuf)
        unsigned long long kb = wkey[par][0];
#pragma unroll
        for (int w2 = 1; w2 < NW; ++w2) kb = umax64(kb, wkey[par][w2]);
        far = (int)(0xFFFFFFFFu ^ (unsigned)kb);
        float4 cc = scoord[far];   // broadcast, conflict-free
        cx = cc.x; cy = cc.y; cz = cc.z;
    }
}

// ---------------- FPS (single wave): no barriers at all ---------------------
template<int ITEMS, int STRIDE>
__global__ __launch_bounds__(64) void fps_wave(
    const float* __restrict__ pts, int npoint,
    int* __restrict__ outIdx, float* __restrict__ outXyz)
{
    constexpr int N = 64 * ITEMS;
    __shared__ float4 scoord[N];

    const int b = blockIdx.x;
    const int tid = threadIdx.x;
    const float* P = pts + (size_t)b * N * STRIDE;

    float px[ITEMS], py[ITEMS], pz[ITEMS], dloc[ITEMS];
#pragma unroll
    for (int w = 0; w < ITEMS; ++w) {
        int n = tid + w * 64;
        float x = P[(size_t)n * STRIDE + 0];
        float y = P[(size_t)n * STRIDE + 1];
        float z = P[(size_t)n * STRIDE + 2];
        px[w] = x; py[w] = y; pz[w] = z;
        scoord[n] = make_float4(x, y, z, 0.f);
        dloc[w] = 1e10f;
    }
    __syncthreads();
    float4 c0 = scoord[0];
    float cx = c0.x, cy = c0.y, cz = c0.z;
    int far = 0;

    for (int i = 0; i < npoint; ++i) {
        if (tid == 0) {
            outIdx[(size_t)b * npoint + i] = far;
            outXyz[((size_t)b * npoint + i) * 3 + 0] = cx;
            outXyz[((size_t)b * npoint + i) * 3 + 1] = cy;
            outXyz[((size_t)b * npoint + i) * 3 + 2] = cz;
        }
        float bestV = -1.0f;
        int bestW = 0;
#pragma unroll
        for (int w = 0; w < ITEMS; ++w) {
            float dx = __fsub_rn(px[w], cx);
            float dy = __fsub_rn(py[w], cy);
            float dz = __fsub_rn(pz[w], cz);
            float d = __fadd_rn(__fadd_rn(__fmul_rn(dx, dx), __fmul_rn(dy, dy)),
                                __fmul_rn(dz, dz));
            float dd = fminf(dloc[w], d);
            dloc[w] = dd;
            if (dd > bestV) { bestV = dd; bestW = w; }
        }
        int bestN = tid + bestW * 64;
        unsigned long long key =
            ((unsigned long long)__float_as_uint(bestV) << 32) |
            (unsigned long long)(0xFFFFFFFFu ^ (unsigned)bestN);
#pragma unroll
        for (int off = 1; off < 64; off <<= 1) {
            unsigned long long ok = __shfl_xor(key, off);
            if (ok > key) key = ok;
        }
        far = (int)(0xFFFFFFFFu ^ (unsigned)key);
        float4 cc = scoord[far];
        cx = cc.x; cy = cc.y; cz = cc.z;
    }
}

// ---------------- query_ball: one wave per center ----------------
__global__ __launch_bounds__(256) void query_ball_kernel(
    const float* __restrict__ xyz, int stride, int N,
    const float* __restrict__ centers, int nCenters, int S,
    float r2, int nsample, int* __restrict__ outIdx)
{
    int gw = (blockIdx.x * 256 + threadIdx.x) >> 6;
    int lane = threadIdx.x & 63;
    if (gw >= nCenters) return;
    int b = gw / S;
    const float* P = xyz + (size_t)b * N * stride;
    float cx = centers[(size_t)gw * 3 + 0];
    float cy = centers[(size_t)gw * 3 + 1];
    float cz = centers[(size_t)gw * 3 + 2];
    int* out = outIdx + (size_t)gw * nsample;
    int cnt = 0;
    int firstIdx = 0;
    bool haveFirst = false;
    for (int base = 0; base < N && cnt < nsample; base += 64) {
        int n = base + lane;
        bool inb = false;
        if (n < N) {
            float dx = __fsub_rn(cx, P[(size_t)n * stride + 0]);
            float dy = __fsub_rn(cy, P[(size_t)n * stride + 1]);
            float dz = __fsub_rn(cz, P[(size_t)n * stride + 2]);
            float d = __fadd_rn(__fadd_rn(__fmul_rn(dx, dx), __fmul_rn(dy, dy)),
                                __fmul_rn(dz, dz));
            inb = !(d > r2);
        }
        unsigned long long mask = __ballot(inb);
        if (mask) {
            if (!haveFirst) { firstIdx = base + __builtin_ctzll(mask); haveFirst = true; }
            if (inb) {
                int pos = cnt + __builtin_popcountll(mask & ((1ull << lane) - 1ull));
                if (pos < nsample) out[pos] = n;
            }
            cnt += (int)__builtin_popcountll(mask);
        }
    }
    if (cnt > nsample) cnt = nsample;
    for (int p = cnt + lane; p < nsample; p += 64) out[p] = firstIdx;
}

// ---------------- grouping kernels ----------------
__global__ __launch_bounds__(256) void group1_kernel(
    const float* __restrict__ in, const int* __restrict__ qb,
    const float* __restrict__ ctr, float* __restrict__ out)
{
    int i = blockIdx.x * 256 + threadIdx.x;
    if (i >= 8 * 512 * 32) return;
    int bs = i / 32;
    int b = i / (512 * 32);
    int idx = qb[i];
    idx = (idx < 0) ? 0 : (idx > 4095 ? 4095 : idx);
    const float* p = in + ((size_t)b * 4096 + idx) * 4;
    const float* c = ctr + (size_t)bs * 3;
    float* o = out + (size_t)i * 4;
    o[0] = __fsub_rn(p[0], c[0]);
    o[1] = __fsub_rn(p[1], c[1]);
    o[2] = __fsub_rn(p[2], c[2]);
    o[3] = p[3];
}

__global__ __launch_bounds__(256) void group2_kernel(
    const float* __restrict__ xyz, const float* __restrict__ feat,
    const int* __restrict__ qb, const float* __restrict__ ctr,
    float* __restrict__ out)
{
    int i = blockIdx.x * 256 + threadIdx.x;
    if (i >= 65536 * 131) return;
    int sk = i / 131;
    int c = i - sk * 131;
    int b = sk / (128 * 64);
    int bs = sk / 64;
    int idx = qb[sk];
    idx = (idx < 0) ? 0 : (idx > 511 ? 511 : idx);
    float v;
    if (c < 3) v = __fsub_rn(xyz[((size_t)b * 512 + idx) * 3 + c], ctr[(size_t)bs * 3 + c]);
    else       v = feat[((size_t)b * 512 + idx) * 128 + (c - 3)];
    out[i] = v;
}

__global__ __launch_bounds__(256) void group3_kernel(
    const float* __restrict__ ctr2, const float* __restrict__ feat2,
    float* __restrict__ out)
{
    int i = blockIdx.x * 256 + threadIdx.x;
    if (i >= 1024 * 259) return;
    int sk = i / 259;
    int c = i - sk * 259;
    out[i] = (c < 3) ? ctr2[(size_t)sk * 3 + c] : feat2[(size_t)sk * 256 + (c - 3)];
}

// ---------------- MFMA GEMM (split-bf16): Y = act(X) * W^T -----------------
// act(x) = applyAct ? relu(x*scale[c]+shift[c]) : x  (BN of PREVIOUS layer),
// applied in f32 during staging, then split into (hi, lo) bf16 planes.
// D = Ah*Bh + Ah*Bl + Al*Bh  (lo*lo dropped, ~2^-16 relative — negligible).
// Block 128(M) x 128(O), 4 waves in 64x64 quadrants, 4x4 of 16x16x32 mfma.
// LDS rows pitch 40 bf16 (80 B): 16B-aligned b128 frag reads, <=2-way banks.
// A-frag: lane m=lane&15, k=quad*8+j.  C/D: col=lane&15, row=quad*4+reg.
// M must be a multiple of 128 (true for all 9 layers).
__global__ __launch_bounds__(256) void gemm_mfma(
    const float* __restrict__ X, const float* __restrict__ W,
    float* __restrict__ Y,
    const float* __restrict__ scale, const float* __restrict__ shift,
    int applyAct, int M, int C, int O)
{
    constexpr int BK = 32;
    constexpr int PITCH = 40;
    __shared__ __align__(16) unsigned short sAh[128 * PITCH];
    __shared__ __align__(16) unsigned short sAl[128 * PITCH];
    __shared__ __align__(16) unsigned short sBh[128 * PITCH];
    __shared__ __align__(16) unsigned short sBl[128 * PITCH];

    const int tid = threadIdx.x;
    const int lane = tid & 63;
    const int wid = tid >> 6;
    const int col15 = lane & 15;
    const int quad = lane >> 4;
    const int wm = (wid >> 1) * 64;
    const int wo = (wid & 1) * 64;
    const int m0 = blockIdx.x * 128;
    const int o0 = blockIdx.y * 128;
    const int srow = tid >> 3;          // 0..31
    const int scol = (tid & 7) * 4;     // 0,4,...,28

    f32x4 acc[4][4];
#pragma unroll
    for (int mt = 0; mt < 4; ++mt)
#pragma unroll
        for (int ot = 0; ot < 4; ++ot)
            acc[mt][ot] = {0.f, 0.f, 0.f, 0.f};

    for (int k0 = 0; k0 < C; k0 += BK) {
        // stage A (X rows): f32 -> act -> (hi, lo) bf16
#pragma unroll
        for (int i = 0; i < 4; ++i) {
            int r = srow + i * 32;
            const float* xr = X + (size_t)(m0 + r) * C;
            ushort4 hh, hl;
            unsigned short h[4], l[4];
#pragma unroll
            for (int j = 0; j < 4; ++j) {
                int c = k0 + scol + j;
                float v = 0.f;
                if (c < C) {
                    v = xr[c];
                    if (applyAct) v = fmaxf(v * scale[c] + shift[c], 0.f);
                }
                f2bf_split(v, h[j], l[j]);
            }
            hh.x = h[0]; hh.y = h[1]; hh.z = h[2]; hh.w = h[3];
            hl.x = l[0]; hl.y = l[1]; hl.z = l[2]; hl.w = l[3];
            *(ushort4*)&sAh[r * PITCH + scol] = hh;
            *(ushort4*)&sAl[r * PITCH + scol] = hl;
        }
        // stage B (W rows), zero rows beyond O
#pragma unroll
        for (int i = 0; i < 4; ++i) {
            int r = srow + i * 32;
            int o = o0 + r;
            const float* wr = W + (size_t)o * C;
            ushort4 hh, hl;
            unsigned short h[4], l[4];
#pragma unroll
            for (int j = 0; j < 4; ++j) {
                int c = k0 + scol + j;
                float v = 0.f;
                if (o < O && c < C) v = wr[c];
                f2bf_split(v, h[j], l[j]);
            }
            hh.x = h[0]; hh.y = h[1]; hh.z = h[2]; hh.w = h[3];
            hl.x = l[0]; hl.y = l[1]; hl.z = l[2]; hl.w = l[3];
            *(ushort4*)&sBh[r * PITCH + scol] = hh;
            *(ushort4*)&sBl[r * PITCH + scol] = hl;
        }
        __syncthreads();
        s16x8 ah[4], al[4], bh[4], bl[4];
#pragma unroll
        for (int mt = 0; mt < 4; ++mt) {
            int rowoff = (wm + mt * 16 + col15) * PITCH + quad * 8;
            ah[mt] = *(const s16x8*)&sAh[rowoff];
            al[mt] = *(const s16x8*)&sAl[rowoff];
        }
#pragma unroll
        for (int ot = 0; ot < 4; ++ot) {
            int rowoff = (wo + ot * 16 + col15) * PITCH + quad * 8;
            bh[ot] = *(const s16x8*)&sBh[rowoff];
            bl[ot] = *(const s16x8*)&sBl[rowoff];
        }
#pragma unroll
        for (int mt = 0; mt < 4; ++mt)
#pragma unroll
            for (int ot = 0; ot < 4; ++ot) {
                acc[mt][ot] = __builtin_amdgcn_mfma_f32_16x16x32_bf16(
                    ah[mt], bl[ot], acc[mt][ot], 0, 0, 0);
                acc[mt][ot] = __builtin_amdgcn_mfma_f32_16x16x32_bf16(
                    al[mt], bh[ot], acc[mt][ot], 0, 0, 0);
                acc[mt][ot] = __builtin_amdgcn_mfma_f32_16x16x32_bf16(
                    ah[mt], bh[ot], acc[mt][ot], 0, 0, 0);
            }
        __syncthreads();
    }
#pragma unroll
    for (int mt = 0; mt < 4; ++mt)
#pragma unroll
        for (int ot = 0; ot < 4; ++ot) {
            int og = o0 + wo + ot * 16 + col15;
            if (og < O) {
#pragma unroll
                for (int r = 0; r < 4; ++r) {
                    int mg = m0 + wm + mt * 16 + quad * 4 + r;
                    Y[(size_t)mg * O + og] = acc[mt][ot][r];
                }
            }
        }
}

// ---------------- per-channel partial sum / sumsq (deterministic) ----------
__global__ __launch_bounds__(256) void stats_partial(
    const float* __restrict__ Y, double* __restrict__ part, int M, int O, int YB)
{
    int olane = threadIdx.x & 63;
    int mlane = threadIdx.x >> 6;
    int o = blockIdx.x * 64 + olane;
    int yb = blockIdx.y;
    int mbase = yb * 1024;
    int mend = min(M, mbase + 1024);
    double s = 0.0, s2 = 0.0;
    for (int m = mbase + mlane; m < mend; m += 4) {
        float v = Y[(size_t)m * O + o];
        s += (double)v;
        s2 += (double)v * (double)v;
    }
    __shared__ double sd[512];
    sd[threadIdx.x] = s;
    sd[256 + threadIdx.x] = s2;
    __syncthreads();
    if (mlane == 0) {
        double t  = sd[olane] + sd[64 + olane] + sd[128 + olane] + sd[192 + olane];
        double t2 = sd[256 + olane] + sd[320 + olane] + sd[384 + olane] + sd[448 + olane];
        part[(size_t)o * YB + yb] = t;
        part[(size_t)O * YB + (size_t)o * YB + yb] = t2;
    }
}

__global__ __launch_bounds__(256) void finalize_bn(
    const double* __restrict__ part, const float* __restrict__ g,
    const float* __restrict__ bb, float* __restrict__ scale,
    float* __restrict__ shift, int O, int YB, double invM)
{
    int o = blockIdx.x * 256 + threadIdx.x;
    if (o >= O) return;
    double s = 0.0, s2 = 0.0;
    for (int yb = 0; yb < YB; ++yb) {
        s  += part[(size_t)o * YB + yb];
        s2 += part[(size_t)O * YB + (size_t)o * YB + yb];
    }
    double mean = s * invM;
    double var = s2 * invM - mean * mean;
    float varf = (float)var;
    if (varf < 0.f) varf = 0.f;
    float sc = g[o] * rsqrtf(varf + 1e-5f);
    float sh = bb[o] - (float)mean * sc;
    scale[o] = sc;
    shift[o] = sh;
}

__global__ __launch_bounds__(256) void bn_relu_max(
    const float* __restrict__ Y, const float* __restrict__ scale,
    const float* __restrict__ shift, float* __restrict__ out,
    int Stot, int K, int O)
{
    int idx = blockIdx.x * 256 + threadIdx.x;
    if (idx >= Stot * O) return;
    int s = idx / O;
    int o = idx - s * O;
    const float* base = Y + (size_t)s * K * O + o;
    float sc = scale[o], sh = shift[o];
    float mx = 0.f;
    for (int k = 0; k < K; ++k) {
        float v = base[(size_t)k * O] * sc + sh;
        v = fmaxf(v, 0.f);
        mx = fmaxf(mx, v);
    }
    out[idx] = mx;
}

// ============================================================================
extern "C" void kernel_launch(void* const* d_in, const int* in_sizes, int n_in,
                              void* d_out, int out_size, void* d_ws, size_t ws_size,
                              hipStream_t stream)
{
    const float* xin = (const float*)d_in[0];
    const float* w[9]; const float* g[9]; const float* bb[9];
    for (int i = 0; i < 9; ++i) {
        w[i]  = (const float*)d_in[1 + 3 * i];
        g[i]  = (const float*)d_in[2 + 3 * i];
        bb[i] = (const float*)d_in[3 + 3 * i];
    }

    char* base = (char*)d_ws;
    size_t off = 0;
    auto alloc = [&](size_t bytes) -> void* {
        void* p = base + off;
        off = (off + bytes + 255) & ~(size_t)255;
        return p;
    };
    int*    fps1   = (int*)alloc((size_t)4096 * 4);
    int*    qb1    = (int*)alloc((size_t)131072 * 4);
    int*    fps2   = (int*)alloc((size_t)1024 * 4);
    int*    qb2    = (int*)alloc((size_t)65536 * 4);
    float*  nx1    = (float*)alloc((size_t)12288 * 4);
    float*  nx2    = (float*)alloc((size_t)3072 * 4);
    float*  feat1  = (float*)alloc((size_t)524288 * 4);
    float*  feat2  = (float*)alloc((size_t)262144 * 4);
    double* part   = (double*)alloc((size_t)65536 * 8);
    float*  scales = (float*)alloc((size_t)9 * 1024 * 4);
    float*  shifts = (float*)alloc((size_t)9 * 1024 * 4);
    float*  A      = (float*)alloc((size_t)16777216 * 4);
    float*  BG     = (float*)alloc((size_t)8585216 * 4);
    if (off > ws_size) return;

    // Every call must be bit-identical regardless of harness ws poison.
    hipMemsetAsync(d_ws, 0, off, stream);

    // ---------------- SA1 ----------------
    fps_block<256, 16, 4><<<8, 256, 0, stream>>>(xin, 512, fps1, nx1);
    query_ball_kernel<<<(8 * 512 * 64) / 256, 256, 0, stream>>>(
        xin, 4, 4096, nx1, 8 * 512, 512, 0.04f, 32, qb1);
    group1_kernel<<<131072 / 256, 256, 0, stream>>>(xin, qb1, nx1, BG);

    gemm_mfma<<<dim3(1024, 1), 256, 0, stream>>>(BG, w[0], A, nullptr, nullptr, 0, 131072, 4, 64);
    stats_partial<<<dim3(1, 128), 256, 0, stream>>>(A, part, 131072, 64, 128);
    finalize_bn<<<1, 256, 0, stream>>>(part, g[0], bb[0], scales + 0 * 1024, shifts + 0 * 1024, 64, 128, 1.0 / 131072.0);
    gemm_mfma<<<dim3(1024, 1), 256, 0, stream>>>(A, w[1], BG, scales + 0 * 1024, shifts + 0 * 1024, 1, 131072, 64, 64);
    stats_partial<<<dim3(1, 128), 256, 0, stream>>>(BG, part, 131072, 64, 128);
    finalize_bn<<<1, 256, 0, stream>>>(part, g[1], bb[1], scales + 1 * 1024, shifts + 1 * 1024, 64, 128, 1.0 / 131072.0);
    gemm_mfma<<<dim3(1024, 1), 256, 0, stream>>>(BG, w[2], A, scales + 1 * 1024, shifts + 1 * 1024, 1, 131072, 64, 128);
    stats_partial<<<dim3(2, 128), 256, 0, stream>>>(A, part, 131072, 128, 128);
    finalize_bn<<<1, 256, 0, stream>>>(part, g[2], bb[2], scales + 2 * 1024, shifts + 2 * 1024, 128, 128, 1.0 / 131072.0);
    bn_relu_max<<<(4096 * 128) / 256, 256, 0, stream>>>(A, scales + 2 * 1024, shifts + 2 * 1024, feat1, 4096, 32, 128);

    // ---------------- SA2 ----------------
    fps_wave<8, 3><<<8, 64, 0, stream>>>(nx1, 128, fps2, nx2);
    query_ball_kernel<<<(8 * 128 * 64) / 256, 256, 0, stream>>>(
        nx1, 3, 512, nx2, 8 * 128, 128, 0.16f, 64, qb2);
    group2_kernel<<<(65536 * 131) / 256, 256, 0, stream>>>(nx1, feat1, qb2, nx2, BG);

    gemm_mfma<<<dim3(512, 1), 256, 0, stream>>>(BG, w[3], A, nullptr, nullptr, 0, 65536, 131, 128);
    stats_partial<<<dim3(2, 64), 256, 0, stream>>>(A, part, 65536, 128, 64);
    finalize_bn<<<1, 256, 0, stream>>>(part, g[3], bb[3], scales + 3 * 1024, shifts + 3 * 1024, 128, 64, 1.0 / 65536.0);
    gemm_mfma<<<dim3(512, 1), 256, 0, stream>>>(A, w[4], BG, scales + 3 * 1024, shifts + 3 * 1024, 1, 65536, 128, 128);
    stats_partial<<<dim3(2, 64), 256, 0, stream>>>(BG, part, 65536, 128, 64);
    finalize_bn<<<1, 256, 0, stream>>>(part, g[4], bb[4], scales + 4 * 1024, shifts + 4 * 1024, 128, 64, 1.0 / 65536.0);
    gemm_mfma<<<dim3(512, 2), 256, 0, stream>>>(BG, w[5], A, scales + 4 * 1024, shifts + 4 * 1024, 1, 65536, 128, 256);
    stats_partial<<<dim3(4, 64), 256, 0, stream>>>(A, part, 65536, 256, 64);
    finalize_bn<<<1, 256, 0, stream>>>(part, g[5], bb[5], scales + 5 * 1024, shifts + 5 * 1024, 256, 64, 1.0 / 65536.0);
    bn_relu_max<<<(1024 * 256) / 256, 256, 0, stream>>>(A, scales + 5 * 1024, shifts + 5 * 1024, feat2, 1024, 64, 256);

    // ---------------- SA3 (group_all) ----------------
    group3_kernel<<<(1024 * 259 + 255) / 256, 256, 0, stream>>>(nx2, feat2, BG);

    gemm_mfma<<<dim3(8, 2), 256, 0, stream>>>(BG, w[6], A, nullptr, nullptr, 0, 1024, 259, 256);
    stats_partial<<<dim3(4, 1), 256, 0, stream>>>(A, part, 1024, 256, 1);
    finalize_bn<<<1, 256, 0, stream>>>(part, g[6], bb[6], scales + 6 * 1024, shifts + 6 * 1024, 256, 1, 1.0 / 1024.0);
    gemm_mfma<<<dim3(8, 4), 256, 0, stream>>>(A, w[7], BG, scales + 6 * 1024, shifts + 6 * 1024, 1, 1024, 256, 512);
    stats_partial<<<dim3(8, 1), 256, 0, stream>>>(BG, part, 1024, 512, 1);
    finalize_bn<<<2, 256, 0, stream>>>(part, g[7], bb[7], scales + 7 * 1024, shifts + 7 * 1024, 512, 1, 1.0 / 1024.0);
    gemm_mfma<<<dim3(8, 8), 256, 0, stream>>>(BG, w[8], A, scales + 7 * 1024, shifts + 7 * 1024, 1, 1024, 512, 1024);
    stats_partial<<<dim3(16, 1), 256, 0, stream>>>(A, part, 1024, 1024, 1);
    finalize_bn<<<4, 256, 0, stream>>>(part, g[8], bb[8], scales + 8 * 1024, shifts + 8 * 1024, 1024, 1, 1.0 / 1024.0);
    bn_relu_max<<<(8 * 1024) / 256, 256, 0, stream>>>(A, scales + 8 * 1024, shifts + 8 * 1024, (float*)d_out, 8, 128, 1024);
}

// Round 7
// 1519.252 us; speedup vs baseline: 1.6877x; 1.1670x over previous
//
#include <hip/hip_runtime.h>

// ============================================================================
// TemporalPointNet (PointNet++ style) forward on MI355X.
// B=2, T=4 -> BT=8 "batches", N=4096 points, 4 coords (xyz + t).
// SA1: npoint=512, r=0.2, K=32, C_in=4,  MLP 64,64,128
// SA2: npoint=128, r=0.4, K=64, C_in=131, MLP 128,128,256
// SA3: group_all,          K=128, C_in=259, MLP 256,512,1024
// Output: (2,4,1024) f32 = 8192 floats.
//
// R7: (1) FPS argmax via DPP wave reduction (row_shr + row_bcast, ~12 VALU)
// instead of 6 dependent ds_bpermute pairs — kills the dominant latency.
// (2) GEMM inputs pre-split into bf16 hi/lo planes once per layer (prep_act /
// group*_split / prep_w) — hot loop is pure loads+ds+MFMA, no per-tile
// conversion VALU, W no longer re-split per M-block. Same split-bf16 triple
// MFMA (Ah*Bl + Al*Bh + Ah*Bh) -> same numerics as R6 (absmax 0.031).
// ============================================================================

typedef short s16x8 __attribute__((ext_vector_type(8)));
typedef float f32x4 __attribute__((ext_vector_type(4)));

__device__ __forceinline__ unsigned short f2bf_rne(float f) {
    unsigned u = __float_as_uint(f);
    u += 0x7FFFu + ((u >> 16) & 1u);
    return (unsigned short)(u >> 16);
}
// split f32 -> (hi, lo) bf16 pair: hi = rne(v), lo = rne(v - hi)
__device__ __forceinline__ void f2bf_split(float v, unsigned short& hi,
                                           unsigned short& lo) {
    unsigned u = __float_as_uint(v);
    unsigned r = u + 0x7FFFu + ((u >> 16) & 1u);
    hi = (unsigned short)(r >> 16);
    float vh = __uint_as_float(r & 0xFFFF0000u);
    lo = f2bf_rne(v - vh);
}

__device__ __forceinline__ unsigned long long umax64(unsigned long long a,
                                                     unsigned long long b) {
    return a > b ? a : b;
}

// Wave64 max-reduce via DPP (LLVM atomic-optimizer sequence). Result valid in
// lane 63. Identity 0 is safe: all reduced values are >= 0 and update_dpp's
// old=0 lanes are re-maxed with the previous value.
__device__ __forceinline__ unsigned wred_umax63(unsigned v) {
    unsigned t;
    t = (unsigned)__builtin_amdgcn_update_dpp(0, (int)v, 0x111, 0xf, 0xf, true); if (t > v) v = t;
    t = (unsigned)__builtin_amdgcn_update_dpp(0, (int)v, 0x112, 0xf, 0xf, true); if (t > v) v = t;
    t = (unsigned)__builtin_amdgcn_update_dpp(0, (int)v, 0x114, 0xf, 0xf, true); if (t > v) v = t;
    t = (unsigned)__builtin_amdgcn_update_dpp(0, (int)v, 0x118, 0xf, 0xf, true); if (t > v) v = t;
    t = (unsigned)__builtin_amdgcn_update_dpp(0, (int)v, 0x142, 0xa, 0xf, true); if (t > v) v = t;
    t = (unsigned)__builtin_amdgcn_update_dpp(0, (int)v, 0x143, 0xc, 0xf, true); if (t > v) v = t;
    return v;
}

// Wave argmax of (dist, min-index): returns (vmaxBits, ~n) as uniform pair.
// dist >= 0 so float bit order == value order. Exact first-occurrence argmax.
__device__ __forceinline__ void wave_argmax(unsigned dbits, unsigned nInv,
                                            unsigned& vmax, unsigned& iInv) {
    unsigned m = wred_umax63(dbits);
    vmax = (unsigned)__builtin_amdgcn_readlane((int)m, 63);
    unsigned cand = (dbits == vmax) ? nInv : 0u;
    unsigned im = wred_umax63(cand);
    iInv = (unsigned)__builtin_amdgcn_readlane((int)im, 63);
}

// ---------------- FPS (multi-wave): one block (NT thr) per batch ------------
// Matches jnp semantics: dist init 1e10, d = ((dx^2+dy^2)+dz^2) with rn ops
// (no fma), argmax picks FIRST occurrence of max (lowest index on ties).
template<int NT, int ITEMS, int STRIDE>
__global__ __launch_bounds__(NT) void fps_block(
    const float* __restrict__ pts, int npoint,
    int* __restrict__ outIdx, float* __restrict__ outXyz)
{
    constexpr int N = NT * ITEMS;
    constexpr int NW = NT / 64;
    __shared__ float4 scoord[N];
    __shared__ unsigned long long wkey[2][NW];

    const int b = blockIdx.x;
    const int tid = threadIdx.x;
    const int wid = tid >> 6;
    const int lane = tid & 63;
    const float* P = pts + (size_t)b * N * STRIDE;

    float px[ITEMS], py[ITEMS], pz[ITEMS], dloc[ITEMS];
#pragma unroll
    for (int w = 0; w < ITEMS; ++w) {
        int n = tid + w * NT;
        float x, y, z;
        if (STRIDE == 4) {
            float4 v = *(const float4*)(P + (size_t)n * 4);
            x = v.x; y = v.y; z = v.z;
        } else {
            x = P[(size_t)n * STRIDE + 0];
            y = P[(size_t)n * STRIDE + 1];
            z = P[(size_t)n * STRIDE + 2];
        }
        px[w] = x; py[w] = y; pz[w] = z;
        scoord[n] = make_float4(x, y, z, 0.f);
        dloc[w] = 1e10f;
    }
    __syncthreads();
    float4 c0 = scoord[0];
    float cx = c0.x, cy = c0.y, cz = c0.z;
    int far = 0;

    for (int i = 0; i < npoint; ++i) {
        if (tid == 0) {
            outIdx[(size_t)b * npoint + i] = far;
            outXyz[((size_t)b * npoint + i) * 3 + 0] = cx;
            outXyz[((size_t)b * npoint + i) * 3 + 1] = cy;
            outXyz[((size_t)b * npoint + i) * 3 + 2] = cz;
        }
        float bestV = -1.0f;
        int bestW = 0;
#pragma unroll
        for (int w = 0; w < ITEMS; ++w) {
            float dx = __fsub_rn(px[w], cx);
            float dy = __fsub_rn(py[w], cy);
            float dz = __fsub_rn(pz[w], cz);
            float d = __fadd_rn(__fadd_rn(__fmul_rn(dx, dx), __fmul_rn(dy, dy)),
                                __fmul_rn(dz, dz));
            float dd = fminf(dloc[w], d);
            dloc[w] = dd;
            if (dd > bestV) { bestV = dd; bestW = w; }  // strict > : lowest w kept
        }
        int bestN = tid + bestW * NT;   // n grows with w -> min n on tie
        unsigned vmax, iInv;
        wave_argmax(__float_as_uint(bestV), 0xFFFFFFFFu ^ (unsigned)bestN,
                    vmax, iInv);
        const int par = i & 1;
        if (lane == 0)
            wkey[par][wid] = ((unsigned long long)vmax << 32) | iInv;
        __syncthreads();   // single barrier per iteration (parity dbuf)
        unsigned long long kb = wkey[par][0];
#pragma unroll
        for (int w2 = 1; w2 < NW; ++w2) kb = umax64(kb, wkey[par][w2]);
        far = (int)(0xFFFFFFFFu ^ (unsigned)kb);
        float4 cc = scoord[far];   // broadcast, conflict-free
        cx = cc.x; cy = cc.y; cz = cc.z;
    }
}

// ---------------- FPS (single wave): no barriers at all ---------------------
template<int ITEMS, int STRIDE>
__global__ __launch_bounds__(64) void fps_wave(
    const float* __restrict__ pts, int npoint,
    int* __restrict__ outIdx, float* __restrict__ outXyz)
{
    constexpr int N = 64 * ITEMS;
    __shared__ float4 scoord[N];

    const int b = blockIdx.x;
    const int tid = threadIdx.x;
    const float* P = pts + (size_t)b * N * STRIDE;

    float px[ITEMS], py[ITEMS], pz[ITEMS], dloc[ITEMS];
#pragma unroll
    for (int w = 0; w < ITEMS; ++w) {
        int n = tid + w * 64;
        float x = P[(size_t)n * STRIDE + 0];
        float y = P[(size_t)n * STRIDE + 1];
        float z = P[(size_t)n * STRIDE + 2];
        px[w] = x; py[w] = y; pz[w] = z;
        scoord[n] = make_float4(x, y, z, 0.f);
        dloc[w] = 1e10f;
    }
    __syncthreads();
    float4 c0 = scoord[0];
    float cx = c0.x, cy = c0.y, cz = c0.z;
    int far = 0;

    for (int i = 0; i < npoint; ++i) {
        if (tid == 0) {
            outIdx[(size_t)b * npoint + i] = far;
            outXyz[((size_t)b * npoint + i) * 3 + 0] = cx;
            outXyz[((size_t)b * npoint + i) * 3 + 1] = cy;
            outXyz[((size_t)b * npoint + i) * 3 + 2] = cz;
        }
        float bestV = -1.0f;
        int bestW = 0;
#pragma unroll
        for (int w = 0; w < ITEMS; ++w) {
            float dx = __fsub_rn(px[w], cx);
            float dy = __fsub_rn(py[w], cy);
            float dz = __fsub_rn(pz[w], cz);
            float d = __fadd_rn(__fadd_rn(__fmul_rn(dx, dx), __fmul_rn(dy, dy)),
                                __fmul_rn(dz, dz));
            float dd = fminf(dloc[w], d);
            dloc[w] = dd;
            if (dd > bestV) { bestV = dd; bestW = w; }
        }
        int bestN = tid + bestW * 64;
        unsigned vmax, iInv;
        wave_argmax(__float_as_uint(bestV), 0xFFFFFFFFu ^ (unsigned)bestN,
                    vmax, iInv);
        far = (int)(0xFFFFFFFFu ^ iInv);
        float4 cc = scoord[far];
        cx = cc.x; cy = cc.y; cz = cc.z;
    }
}

// ---------------- query_ball: one wave per center ----------------
__global__ __launch_bounds__(256) void query_ball_kernel(
    const float* __restrict__ xyz, int stride, int N,
    const float* __restrict__ centers, int nCenters, int S,
    float r2, int nsample, int* __restrict__ outIdx)
{
    int gw = (blockIdx.x * 256 + threadIdx.x) >> 6;
    int lane = threadIdx.x & 63;
    if (gw >= nCenters) return;
    int b = gw / S;
    const float* P = xyz + (size_t)b * N * stride;
    float cx = centers[(size_t)gw * 3 + 0];
    float cy = centers[(size_t)gw * 3 + 1];
    float cz = centers[(size_t)gw * 3 + 2];
    int* out = outIdx + (size_t)gw * nsample;
    int cnt = 0;
    int firstIdx = 0;
    bool haveFirst = false;
    for (int base = 0; base < N && cnt < nsample; base += 64) {
        int n = base + lane;
        bool inb = false;
        if (n < N) {
            float dx = __fsub_rn(cx, P[(size_t)n * stride + 0]);
            float dy = __fsub_rn(cy, P[(size_t)n * stride + 1]);
            float dz = __fsub_rn(cz, P[(size_t)n * stride + 2]);
            float d = __fadd_rn(__fadd_rn(__fmul_rn(dx, dx), __fmul_rn(dy, dy)),
                                __fmul_rn(dz, dz));
            inb = !(d > r2);
        }
        unsigned long long mask = __ballot(inb);
        if (mask) {
            if (!haveFirst) { firstIdx = base + __builtin_ctzll(mask); haveFirst = true; }
            if (inb) {
                int pos = cnt + __builtin_popcountll(mask & ((1ull << lane) - 1ull));
                if (pos < nsample) out[pos] = n;
            }
            cnt += (int)__builtin_popcountll(mask);
        }
    }
    if (cnt > nsample) cnt = nsample;
    for (int p = cnt + lane; p < nsample; p += 64) out[p] = firstIdx;
}

// ---------------- grouping kernels (write split bf16 planes) ---------------
// grouped1: (8*512*32, CP=8) = [xyz - center, t, 0,0,0,0]
__global__ __launch_bounds__(256) void group1_split(
    const float* __restrict__ in, const int* __restrict__ qb,
    const float* __restrict__ ctr,
    unsigned short* __restrict__ Ph, unsigned short* __restrict__ Pl)
{
    int i = blockIdx.x * 256 + threadIdx.x;
    if (i >= 8 * 512 * 32) return;
    int bs = i / 32;
    int b = i / (512 * 32);
    int idx = qb[i];
    idx = (idx < 0) ? 0 : (idx > 4095 ? 4095 : idx);
    float4 p = *(const float4*)(in + ((size_t)b * 4096 + idx) * 4);
    const float* c = ctr + (size_t)bs * 3;
    float v[8];
    v[0] = __fsub_rn(p.x, c[0]);
    v[1] = __fsub_rn(p.y, c[1]);
    v[2] = __fsub_rn(p.z, c[2]);
    v[3] = p.w;
    v[4] = v[5] = v[6] = v[7] = 0.f;
    unsigned short h[8], l[8];
#pragma unroll
    for (int j = 0; j < 8; ++j) f2bf_split(v[j], h[j], l[j]);
    *(ushort4*)(Ph + (size_t)i * 8)     = make_ushort4(h[0], h[1], h[2], h[3]);
    *(ushort4*)(Ph + (size_t)i * 8 + 4) = make_ushort4(h[4], h[5], h[6], h[7]);
    *(ushort4*)(Pl + (size_t)i * 8)     = make_ushort4(l[0], l[1], l[2], l[3]);
    *(ushort4*)(Pl + (size_t)i * 8 + 4) = make_ushort4(l[4], l[5], l[6], l[7]);
}

// grouped2: (8*128*64, CP=136) = [xyz - center (3), feat1 (128), 0-pad (5)]
__global__ __launch_bounds__(256) void group2_split(
    const float* __restrict__ xyz, const float* __restrict__ feat,
    const int* __restrict__ qb, const float* __restrict__ ctr,
    unsigned short* __restrict__ Ph, unsigned short* __restrict__ Pl)
{
    int i = blockIdx.x * 256 + threadIdx.x;
    if (i >= 65536 * 136) return;
    int sk = i / 136;
    int c = i - sk * 136;
    int b = sk / (128 * 64);
    int bs = sk / 64;
    int idx = qb[sk];
    idx = (idx < 0) ? 0 : (idx > 511 ? 511 : idx);
    float v = 0.f;
    if (c < 3)        v = __fsub_rn(xyz[((size_t)b * 512 + idx) * 3 + c], ctr[(size_t)bs * 3 + c]);
    else if (c < 131) v = feat[((size_t)b * 512 + idx) * 128 + (c - 3)];
    unsigned short h, l;
    f2bf_split(v, h, l);
    Ph[i] = h; Pl[i] = l;
}

// grouped3: (8*128, CP=264) = [new_xyz2 (3), feat2 (256), 0-pad (5)]
__global__ __launch_bounds__(256) void group3_split(
    const float* __restrict__ ctr2, const float* __restrict__ feat2,
    unsigned short* __restrict__ Ph, unsigned short* __restrict__ Pl)
{
    int i = blockIdx.x * 256 + threadIdx.x;
    if (i >= 1024 * 264) return;
    int sk = i / 264;
    int c = i - sk * 264;
    float v = 0.f;
    if (c < 3)        v = ctr2[(size_t)sk * 3 + c];
    else if (c < 259) v = feat2[(size_t)sk * 256 + (c - 3)];
    unsigned short h, l;
    f2bf_split(v, h, l);
    Ph[i] = h; Pl[i] = l;
}

// ---------------- weight pre-split: W[O,C] -> padded planes [O,CP] ---------
__global__ __launch_bounds__(256) void prep_w(
    const float* __restrict__ w, unsigned short* __restrict__ wh,
    unsigned short* __restrict__ wl, int O, int C, int CP)
{
    int i = blockIdx.x * 256 + threadIdx.x;
    if (i >= O * CP) return;
    int o = i / CP;
    int c = i - o * CP;
    float v = (c < C) ? w[(size_t)o * C + c] : 0.f;
    unsigned short h, l;
    f2bf_split(v, h, l);
    wh[i] = h; wl[i] = l;
}

// ---------------- act + split: Y f32 -> next-layer input planes ------------
// v = relu(Y*scale[c] + shift[c]); C multiple of 4.
__global__ __launch_bounds__(256) void prep_act(
    const float* __restrict__ Y, const float* __restrict__ scale,
    const float* __restrict__ shift,
    unsigned short* __restrict__ Ph, unsigned short* __restrict__ Pl,
    int total4, int C)
{
    int idx = blockIdx.x * 256 + threadIdx.x;
    if (idx >= total4) return;
    int i4 = idx * 4;
    float4 y = *(const float4*)(Y + i4);
    int c = i4 % C;
    float v0 = fmaxf(y.x * scale[c + 0] + shift[c + 0], 0.f);
    float v1 = fmaxf(y.y * scale[c + 1] + shift[c + 1], 0.f);
    float v2 = fmaxf(y.z * scale[c + 2] + shift[c + 2], 0.f);
    float v3 = fmaxf(y.w * scale[c + 3] + shift[c + 3], 0.f);
    unsigned short h[4], l[4];
    f2bf_split(v0, h[0], l[0]);
    f2bf_split(v1, h[1], l[1]);
    f2bf_split(v2, h[2], l[2]);
    f2bf_split(v3, h[3], l[3]);
    *(ushort4*)(Ph + i4) = make_ushort4(h[0], h[1], h[2], h[3]);
    *(ushort4*)(Pl + i4) = make_ushort4(l[0], l[1], l[2], l[3]);
}

// ---------------- MFMA GEMM (split-bf16, pre-split inputs) -----------------
// Y[M,O] = A[M,CP] * B[O,CP]^T where A,B given as bf16 hi/lo planes.
// D = Ah*Bl + Al*Bh + Ah*Bh (same order as R6 -> identical rounding).
// Block 128x128, 4 waves in 64x64 quadrants, 4x4 of 16x16x32 mfma, BK=32.
// LDS pitch 40 bf16 (80 B) -> 16B-aligned b128 frags, <=2-way banks (free).
// M multiple of 128; CP multiple of 8 (zero-padded planes).
__global__ __launch_bounds__(256) void gemm_mfma(
    const unsigned short* __restrict__ Ah, const unsigned short* __restrict__ Al,
    const unsigned short* __restrict__ Bh, const unsigned short* __restrict__ Bl,
    float* __restrict__ Y, int M, int CP, int O)
{
    constexpr int BK = 32;
    constexpr int PITCH = 40;
    __shared__ __align__(16) unsigned short sAh[128 * PITCH];
    __shared__ __align__(16) unsigned short sAl[128 * PITCH];
    __shared__ __align__(16) unsigned short sBh[128 * PITCH];
    __shared__ __align__(16) unsigned short sBl[128 * PITCH];

    const int tid = threadIdx.x;
    const int lane = tid & 63;
    const int wid = tid >> 6;
    const int col15 = lane & 15;
    const int quad = lane >> 4;
    const int wm = (wid >> 1) * 64;
    const int wo = (wid & 1) * 64;
    const int m0 = blockIdx.x * 128;
    const int o0 = blockIdx.y * 128;
    const int lr = tid >> 2;            // 0..63
    const int lc = (tid & 3) * 8;       // 0,8,16,24

    f32x4 acc[4][4];
#pragma unroll
    for (int mt = 0; mt < 4; ++mt)
#pragma unroll
        for (int ot = 0; ot < 4; ++ot)
            acc[mt][ot] = {0.f, 0.f, 0.f, 0.f};

    for (int k0 = 0; k0 < CP; k0 += BK) {
#pragma unroll
        for (int it = 0; it < 2; ++it) {
            int r = lr + it * 64;
            int c = k0 + lc;
            uint4 vh = {0, 0, 0, 0}, vl = {0, 0, 0, 0};
            if (c < CP) {
                size_t goff = (size_t)(m0 + r) * CP + c;
                vh = *(const uint4*)(Ah + goff);
                vl = *(const uint4*)(Al + goff);
            }
            *(uint4*)&sAh[r * PITCH + lc] = vh;
            *(uint4*)&sAl[r * PITCH + lc] = vl;
        }
#pragma unroll
        for (int it = 0; it < 2; ++it) {
            int r = lr + it * 64;
            int c = k0 + lc;
            int o = o0 + r;
            uint4 vh = {0, 0, 0, 0}, vl = {0, 0, 0, 0};
            if (o < O && c < CP) {
                size_t goff = (size_t)o * CP + c;
                vh = *(const uint4*)(Bh + goff);
                vl = *(const uint4*)(Bl + goff);
            }
            *(uint4*)&sBh[r * PITCH + lc] = vh;
            *(uint4*)&sBl[r * PITCH + lc] = vl;
        }
        __syncthreads();
        s16x8 ah[4], al[4], bh[4], bl[4];
#pragma unroll
        for (int mt = 0; mt < 4; ++mt) {
            int rowoff = (wm + mt * 16 + col15) * PITCH + quad * 8;
            ah[mt] = *(const s16x8*)&sAh[rowoff];
            al[mt] = *(const s16x8*)&sAl[rowoff];
        }
#pragma unroll
        for (int ot = 0; ot < 4; ++ot) {
            int rowoff = (wo + ot * 16 + col15) * PITCH + quad * 8;
            bh[ot] = *(const s16x8*)&sBh[rowoff];
            bl[ot] = *(const s16x8*)&sBl[rowoff];
        }
#pragma unroll
        for (int mt = 0; mt < 4; ++mt)
#pragma unroll
            for (int ot = 0; ot < 4; ++ot) {
                acc[mt][ot] = __builtin_amdgcn_mfma_f32_16x16x32_bf16(
                    ah[mt], bl[ot], acc[mt][ot], 0, 0, 0);
                acc[mt][ot] = __builtin_amdgcn_mfma_f32_16x16x32_bf16(
                    al[mt], bh[ot], acc[mt][ot], 0, 0, 0);
                acc[mt][ot] = __builtin_amdgcn_mfma_f32_16x16x32_bf16(
                    ah[mt], bh[ot], acc[mt][ot], 0, 0, 0);
            }
        __syncthreads();
    }
#pragma unroll
    for (int mt = 0; mt < 4; ++mt)
#pragma unroll
        for (int ot = 0; ot < 4; ++ot) {
            int og = o0 + wo + ot * 16 + col15;
            if (og < O) {
#pragma unroll
                for (int r = 0; r < 4; ++r) {
                    int mg = m0 + wm + mt * 16 + quad * 4 + r;
                    Y[(size_t)mg * O + og] = acc[mt][ot][r];
                }
            }
        }
}

// ---------------- per-channel partial sum / sumsq (deterministic) ----------
__global__ __launch_bounds__(256) void stats_partial(
    const float* __restrict__ Y, double* __restrict__ part, int M, int O, int YB)
{
    int olane = threadIdx.x & 63;
    int mlane = threadIdx.x >> 6;
    int o = blockIdx.x * 64 + olane;
    int yb = blockIdx.y;
    int mbase = yb * 1024;
    int mend = min(M, mbase + 1024);
    double s = 0.0, s2 = 0.0;
    for (int m = mbase + mlane; m < mend; m += 4) {
        float v = Y[(size_t)m * O + o];
        s += (double)v;
        s2 += (double)v * (double)v;
    }
    __shared__ double sd[512];
    sd[threadIdx.x] = s;
    sd[256 + threadIdx.x] = s2;
    __syncthreads();
    if (mlane == 0) {
        double t  = sd[olane] + sd[64 + olane] + sd[128 + olane] + sd[192 + olane];
        double t2 = sd[256 + olane] + sd[320 + olane] + sd[384 + olane] + sd[448 + olane];
        part[(size_t)o * YB + yb] = t;
        part[(size_t)O * YB + (size_t)o * YB + yb] = t2;
    }
}

__global__ __launch_bounds__(256) void finalize_bn(
    const double* __restrict__ part, const float* __restrict__ g,
    const float* __restrict__ bb, float* __restrict__ scale,
    float* __restrict__ shift, int O, int YB, double invM)
{
    int o = blockIdx.x * 256 + threadIdx.x;
    if (o >= O) return;
    double s = 0.0, s2 = 0.0;
    for (int yb = 0; yb < YB; ++yb) {
        s  += part[(size_t)o * YB + yb];
        s2 += part[(size_t)O * YB + (size_t)o * YB + yb];
    }
    double mean = s * invM;
    double var = s2 * invM - mean * mean;
    float varf = (float)var;
    if (varf < 0.f) varf = 0.f;
    float sc = g[o] * rsqrtf(varf + 1e-5f);
    float sh = bb[o] - (float)mean * sc;
    scale[o] = sc;
    shift[o] = sh;
}

__global__ __launch_bounds__(256) void bn_relu_max(
    const float* __restrict__ Y, const float* __restrict__ scale,
    const float* __restrict__ shift, float* __restrict__ out,
    int Stot, int K, int O)
{
    int idx = blockIdx.x * 256 + threadIdx.x;
    if (idx >= Stot * O) return;
    int s = idx / O;
    int o = idx - s * O;
    const float* base = Y + (size_t)s * K * O + o;
    float sc = scale[o], sh = shift[o];
    float mx = 0.f;
    for (int k = 0; k < K; ++k) {
        float v = base[(size_t)k * O] * sc + sh;
        v = fmaxf(v, 0.f);
        mx = fmaxf(mx, v);
    }
    out[idx] = mx;
}

// ============================================================================
extern "C" void kernel_launch(void* const* d_in, const int* in_sizes, int n_in,
                              void* d_out, int out_size, void* d_ws, size_t ws_size,
                              hipStream_t stream)
{
    const float* xin = (const float*)d_in[0];
    const float* w[9]; const float* g[9]; const float* bb[9];
    for (int i = 0; i < 9; ++i) {
        w[i]  = (const float*)d_in[1 + 3 * i];
        g[i]  = (const float*)d_in[2 + 3 * i];
        bb[i] = (const float*)d_in[3 + 3 * i];
    }

    char* base = (char*)d_ws;
    size_t off = 0;
    auto alloc = [&](size_t bytes) -> void* {
        void* p = base + off;
        off = (off + bytes + 255) & ~(size_t)255;
        return p;
    };
    const size_t PLANE_ELEMS = (size_t)65536 * 136;   // 8,912,896 (max input)
    // weight plane offsets (O x CP per layer)
    const int OC[9][3] = {{64,4,8},{64,64,64},{128,64,64},
                          {128,131,136},{128,128,128},{256,128,128},
                          {256,259,264},{512,256,256},{1024,512,512}};
    size_t woff[10]; woff[0] = 0;
    for (int i = 0; i < 9; ++i) woff[i + 1] = woff[i] + (size_t)OC[i][0] * OC[i][2];

    int*    fps1   = (int*)alloc((size_t)4096 * 4);
    int*    qb1    = (int*)alloc((size_t)131072 * 4);
    int*    fps2   = (int*)alloc((size_t)1024 * 4);
    int*    qb2    = (int*)alloc((size_t)65536 * 4);
    float*  nx1    = (float*)alloc((size_t)12288 * 4);
    float*  nx2    = (float*)alloc((size_t)3072 * 4);
    float*  feat1  = (float*)alloc((size_t)524288 * 4);
    float*  feat2  = (float*)alloc((size_t)262144 * 4);
    double* part   = (double*)alloc((size_t)32768 * 8);
    float*  scales = (float*)alloc((size_t)9 * 1024 * 4);
    float*  shifts = (float*)alloc((size_t)9 * 1024 * 4);
    unsigned short* WH = (unsigned short*)alloc(woff[9] * 2);
    unsigned short* WL = (unsigned short*)alloc(woff[9] * 2);
    unsigned short* Ph = (unsigned short*)alloc(PLANE_ELEMS * 2);
    unsigned short* Pl = (unsigned short*)alloc(PLANE_ELEMS * 2);
    float*  A      = (float*)alloc((size_t)16777216 * 4);   // Y (f32), max 131072x128
    if (off > ws_size) return;

    // Every call must be bit-identical regardless of harness ws poison.
    hipMemsetAsync(d_ws, 0, off, stream);

    // ---- weight pre-split (once per launch, independent of pipeline) ----
    for (int i = 0; i < 9; ++i) {
        int n = OC[i][0] * OC[i][2];
        prep_w<<<(n + 255) / 256, 256, 0, stream>>>(
            w[i], WH + woff[i], WL + woff[i], OC[i][0], OC[i][1], OC[i][2]);
    }

    // ---------------- SA1 ----------------
    fps_block<256, 16, 4><<<8, 256, 0, stream>>>(xin, 512, fps1, nx1);
    query_ball_kernel<<<(8 * 512 * 64) / 256, 256, 0, stream>>>(
        xin, 4, 4096, nx1, 8 * 512, 512, 0.04f, 32, qb1);
    group1_split<<<131072 / 256, 256, 0, stream>>>(xin, qb1, nx1, Ph, Pl);

    // L1_0: (131072, CP=8) -> 64
    gemm_mfma<<<dim3(1024, 1), 256, 0, stream>>>(Ph, Pl, WH + woff[0], WL + woff[0], A, 131072, 8, 64);
    stats_partial<<<dim3(1, 128), 256, 0, stream>>>(A, part, 131072, 64, 128);
    finalize_bn<<<1, 256, 0, stream>>>(part, g[0], bb[0], scales + 0 * 1024, shifts + 0 * 1024, 64, 128, 1.0 / 131072.0);
    prep_act<<<(131072 * 64 / 4 + 255) / 256, 256, 0, stream>>>(A, scales + 0 * 1024, shifts + 0 * 1024, Ph, Pl, 131072 * 64 / 4, 64);
    // L1_1: 64 -> 64
    gemm_mfma<<<dim3(1024, 1), 256, 0, stream>>>(Ph, Pl, WH + woff[1], WL + woff[1], A, 131072, 64, 64);
    stats_partial<<<dim3(1, 128), 256, 0, stream>>>(A, part, 131072, 64, 128);
    finalize_bn<<<1, 256, 0, stream>>>(part, g[1], bb[1], scales + 1 * 1024, shifts + 1 * 1024, 64, 128, 1.0 / 131072.0);
    prep_act<<<(131072 * 64 / 4 + 255) / 256, 256, 0, stream>>>(A, scales + 1 * 1024, shifts + 1 * 1024, Ph, Pl, 131072 * 64 / 4, 64);
    // L1_2: 64 -> 128
    gemm_mfma<<<dim3(1024, 1), 256, 0, stream>>>(Ph, Pl, WH + woff[2], WL + woff[2], A, 131072, 64, 128);
    stats_partial<<<dim3(2, 128), 256, 0, stream>>>(A, part, 131072, 128, 128);
    finalize_bn<<<1, 256, 0, stream>>>(part, g[2], bb[2], scales + 2 * 1024, shifts + 2 * 1024, 128, 128, 1.0 / 131072.0);
    bn_relu_max<<<(4096 * 128) / 256, 256, 0, stream>>>(A, scales + 2 * 1024, shifts + 2 * 1024, feat1, 4096, 32, 128);

    // ---------------- SA2 ----------------
    fps_wave<8, 3><<<8, 64, 0, stream>>>(nx1, 128, fps2, nx2);
    query_ball_kernel<<<(8 * 128 * 64) / 256, 256, 0, stream>>>(
        nx1, 3, 512, nx2, 8 * 128, 128, 0.16f, 64, qb2);
    group2_split<<<(65536 * 136) / 256, 256, 0, stream>>>(nx1, feat1, qb2, nx2, Ph, Pl);

    // L2_0: (65536, CP=136) -> 128
    gemm_mfma<<<dim3(512, 1), 256, 0, stream>>>(Ph, Pl, WH + woff[3], WL + woff[3], A, 65536, 136, 128);
    stats_partial<<<dim3(2, 64), 256, 0, stream>>>(A, part, 65536, 128, 64);
    finalize_bn<<<1, 256, 0, stream>>>(part, g[3], bb[3], scales + 3 * 1024, shifts + 3 * 1024, 128, 64, 1.0 / 65536.0);
    prep_act<<<(65536 * 128 / 4 + 255) / 256, 256, 0, stream>>>(A, scales + 3 * 1024, shifts + 3 * 1024, Ph, Pl, 65536 * 128 / 4, 128);
    // L2_1: 128 -> 128
    gemm_mfma<<<dim3(512, 1), 256, 0, stream>>>(Ph, Pl, WH + woff[4], WL + woff[4], A, 65536, 128, 128);
    stats_partial<<<dim3(2, 64), 256, 0, stream>>>(A, part, 65536, 128, 64);
    finalize_bn<<<1, 256, 0, stream>>>(part, g[4], bb[4], scales + 4 * 1024, shifts + 4 * 1024, 128, 64, 1.0 / 65536.0);
    prep_act<<<(65536 * 128 / 4 + 255) / 256, 256, 0, stream>>>(A, scales + 4 * 1024, shifts + 4 * 1024, Ph, Pl, 65536 * 128 / 4, 128);
    // L2_2: 128 -> 256
    gemm_mfma<<<dim3(512, 2), 256, 0, stream>>>(Ph, Pl, WH + woff[5], WL + woff[5], A, 65536, 128, 256);
    stats_partial<<<dim3(4, 64), 256, 0, stream>>>(A, part, 65536, 256, 64);
    finalize_bn<<<1, 256, 0, stream>>>(part, g[5], bb[5], scales + 5 * 1024, shifts + 5 * 1024, 256, 64, 1.0 / 65536.0);
    bn_relu_max<<<(1024 * 256) / 256, 256, 0, stream>>>(A, scales + 5 * 1024, shifts + 5 * 1024, feat2, 1024, 64, 256);

    // ---------------- SA3 (group_all) ----------------
    group3_split<<<(1024 * 264 + 255) / 256, 256, 0, stream>>>(nx2, feat2, Ph, Pl);

    // L3_0: (1024, CP=264) -> 256
    gemm_mfma<<<dim3(8, 2), 256, 0, stream>>>(Ph, Pl, WH + woff[6], WL + woff[6], A, 1024, 264, 256);
    stats_partial<<<dim3(4, 1), 256, 0, stream>>>(A, part, 1024, 256, 1);
    finalize_bn<<<1, 256, 0, stream>>>(part, g[6], bb[6], scales + 6 * 1024, shifts + 6 * 1024, 256, 1, 1.0 / 1024.0);
    prep_act<<<(1024 * 256 / 4 + 255) / 256, 256, 0, stream>>>(A, scales + 6 * 1024, shifts + 6 * 1024, Ph, Pl, 1024 * 256 / 4, 256);
    // L3_1: 256 -> 512
    gemm_mfma<<<dim3(8, 4), 256, 0, stream>>>(Ph, Pl, WH + woff[7], WL + woff[7], A, 1024, 256, 512);
    stats_partial<<<dim3(8, 1), 256, 0, stream>>>(A, part, 1024, 512, 1);
    finalize_bn<<<2, 256, 0, stream>>>(part, g[7], bb[7], scales + 7 * 1024, shifts + 7 * 1024, 512, 1, 1.0 / 1024.0);
    prep_act<<<(1024 * 512 / 4 + 255) / 256, 256, 0, stream>>>(A, scales + 7 * 1024, shifts + 7 * 1024, Ph, Pl, 1024 * 512 / 4, 512);
    // L3_2: 512 -> 1024
    gemm_mfma<<<dim3(8, 8), 256, 0, stream>>>(Ph, Pl, WH + woff[8], WL + woff[8], A, 1024, 512, 1024);
    stats_partial<<<dim3(16, 1), 256, 0, stream>>>(A, part, 1024, 1024, 1);
    finalize_bn<<<4, 256, 0, stream>>>(part, g[8], bb[8], scales + 8 * 1024, shifts + 8 * 1024, 1024, 1, 1.0 / 1024.0);
    bn_relu_max<<<(8 * 1024) / 256, 256, 0, stream>>>(A, scales + 8 * 1024, shifts + 8 * 1024, (float*)d_out, 8, 128, 1024);
}